// Round 1
// baseline (722.482 us; speedup 1.0000x reference)
//
#include <hip/hip_runtime.h>

// Problem constants (fixed by setup_inputs): (B,D,H,W) = (2,256,256,128), fp32.
#define LAMB 0.01f
constexpr int Bc = 2, Dc = 256, Hc = 256, Wc = 128;
constexpr int HWc = Hc * Wc;                 // 32768
constexpr int NELEM = Bc * Dc * HWc;         // 16,777,216

// ---- fused 3-cascade tile geometry ----
constexpr int TD = 8, TH = 8, TW = 32;       // output tile per block
constexpr int RD = TD + 6, RH = TH + 6, RW = TW + 6;  // 14,14,38 (halo 3 each side)
constexpr int RWP = 40;                      // padded W stride (rows 16B-aligned)
constexpr int NROWS = RD * RH;               // 196
constexpr int NTHR = 1024;
constexpr int GDt = Dc / TD, GHt = Hc / TH, GWt = Wc / TW; // 32,32,4
constexpr int NBLK = Bc * GDt * GHt * GWt;   // 8192

static_assert(4 * NROWS * RWP * 4 <= 160 * 1024, "LDS over 160 KiB");
static_assert(NBLK % 8 == 0, "swizzle needs nblk % 8 == 0");

typedef float f4 __attribute__((ext_vector_type(4)));

__device__ __forceinline__ float clipf(float x, float s) {
    return fminf(fmaxf(x, -s), s);
}
__device__ __forceinline__ float zof(float t, float s) { return t + LAMB * (s - t); }
// extrapolated dual update: pn = clip(pold - dz, +-sg); return pn + nt*(pn - pold)
__device__ __forceinline__ float dual_up(float pold, float dz, float sg, float ntc) {
    float pn = clipf(pold - dz, sg);
    return pn + ntc * (pn - pold);
}

__global__ __launch_bounds__(NTHR) void fused3(
    const float* __restrict__ image, const float* __restrict__ sino,
    float* __restrict__ out0, float* __restrict__ out1,
    float* __restrict__ out2, float* __restrict__ out3,
    const float* __restrict__ sigma, const float* __restrict__ nt)
{
    __shared__ float Z[NROWS * RWP];
    __shared__ float P[NROWS * RWP];
    __shared__ float Q[NROWS * RWP];
    __shared__ float S[NROWS * RWP];

    // XCD-contiguous swizzle (bijective: NBLK % 8 == 0)
    int bid = (int)blockIdx.x;
    bid = (bid & 7) * (NBLK >> 3) + (bid >> 3);
    const int wT = bid & (GWt - 1);
    const int hT = (bid >> 2) & (GHt - 1);
    const int dT = (bid >> 7) & (GDt - 1);
    const int b  = bid >> 12;
    const int d0 = dT * TD, h0 = hT * TH, w0 = wT * TW;
    const int base = b * Dc * HWc;

    const float s0 = sigma[0], s1 = sigma[1], s2 = sigma[2], s3 = sigma[3];
    const int tid = (int)threadIdx.x;

    // ---- phase 0: z0 over the full padded region (cols 0..39) ----
    for (int t = tid; t < NROWS * 10; t += NTHR) {
        const int row = t / 10, g = t - row * 10;
        const int rd = row / RH, rh = row - rd * RH;
        const int gd = d0 - 3 + rd, gh = h0 - 3 + rh;
        const bool rowok = ((unsigned)gd < (unsigned)Dc) && ((unsigned)gh < (unsigned)Hc);
        const int rbase = base + gd * HWc + gh * Wc;   // only deref'd when guarded
        f4 z;
#pragma unroll
        for (int k = 0; k < 4; ++k) {
            const int gw = w0 - 3 + g * 4 + k;
            float v = 0.f;
            if (rowok && (unsigned)gw < (unsigned)Wc) {
                const int gix = rbase + gw;
                v = zof(image[gix], sino[gix]);
            }
            z[k] = v;
        }
        *(f4*)&Z[row * RWP + g * 4] = z;
    }
    // out0 = image tile (aligned float4, nontemporal)
    for (int t = tid; t < TD * TH * (TW / 4); t += NTHR) {
        const int g = t & (TW / 4 - 1);
        const int r = t >> 3;
        const int td = r >> 3, th = r & 7;
        const int gix = base + (d0 + td) * HWc + (h0 + th) * Wc + w0 + g * 4;
        __builtin_nontemporal_store(*(const f4*)&image[gix], (f4*)&out0[gix]);
    }
    __syncthreads();

#pragma unroll
    for (int c = 0; c < 3; ++c) {
        const float ntc = nt[c];

        // ---- dual pass: rd,rh in [0,12], 10 W-groups (uniform box; garbage
        //      cells outside the true shrinking box are never read by true cells)
        for (int t = tid; t < 169 * 10; t += NTHR) {
            const int row13 = t / 10, g = t - row13 * 10;
            const int rd = row13 / 13, rh = row13 - (row13 / 13) * 13;
            const int li = (rd * RH + rh) * RWP + g * 4;

            const f4 zc4 = *(const f4*)&Z[li];
            const float z5 = (g < 9) ? Z[li + 4] : 0.f;       // W+4 neighbor
            const f4 zd4 = *(const f4*)&Z[li + RH * RWP];     // rd+1
            const f4 zh4 = *(const f4*)&Z[li + RWP];          // rh+1

            f4 po = {0.f, 0.f, 0.f, 0.f}, qo = po, so = po;
            if (c > 0) {
                po = *(const f4*)&P[li];
                qo = *(const f4*)&Q[li];
                so = *(const f4*)&S[li];
            }
            const int gd = d0 - 3 + rd, gh = h0 - 3 + rh;
            const bool dok = (unsigned)gd < (unsigned)Dc;
            const bool hok = (unsigned)gh < (unsigned)Hc;
            const bool dlast = (gd == Dc - 1), hlast = (gh == Hc - 1);

            f4 pn, qn, sn;
#pragma unroll
            for (int k = 0; k < 4; ++k) {
                const int gw = w0 - 3 + g * 4 + k;
                const bool inb = dok && hok && ((unsigned)gw < (unsigned)Wc);
                const float zck = zc4[k];
                const float zr  = (k == 3) ? z5 : zc4[k + 1];
                const float dzD = dlast ? 0.f : (zd4[k] - zck);
                const float dzH = hlast ? 0.f : (zh4[k] - zck);
                const float dzW = (gw == Wc - 1) ? 0.f : (zr - zck);
                pn[k] = inb ? dual_up(po[k], dzD, s0, ntc) : 0.f;
                qn[k] = inb ? dual_up(qo[k], dzH, s1, ntc) : 0.f;
                sn[k] = inb ? dual_up(so[k], dzW, s2, ntc) : 0.f;
            }
            *(f4*)&P[li] = pn;
            *(f4*)&Q[li] = qn;
            *(f4*)&S[li] = sn;
        }
        __syncthreads();

        // ---- t pass: rd,rh in [1,12]; writes tile outputs; t->z in place ----
        float* outc = (c == 0) ? out1 : ((c == 1) ? out2 : out3);
        for (int t = tid; t < 144 * 10; t += NTHR) {
            const int row12 = t / 10, g = t - row12 * 10;
            const int rdm = row12 / 12;
            const int rd = 1 + rdm, rh = 1 + (row12 - rdm * 12);
            const int li = (rd * RH + rh) * RWP + g * 4;

            const f4 pc = *(const f4*)&P[li];
            const f4 pm = *(const f4*)&P[li - RH * RWP];      // rd-1
            const f4 qc = *(const f4*)&Q[li];
            const f4 qm = *(const f4*)&Q[li - RWP];           // rh-1
            const f4 sc = *(const f4*)&S[li];
            const float sm1 = S[li - 1];                      // rw-1 (li>=560, safe)
            const f4 zc4 = *(const f4*)&Z[li];

            float tn[4];
#pragma unroll
            for (int k = 0; k < 4; ++k) {
                const float smk = (k == 0) ? sm1 : sc[k - 1];
                tn[k] = (pm[k] - pc[k]) + (qm[k] - qc[k]) + (smk - sc[k])
                      + clipf(zc4[k], s3);
            }

            const int gd = d0 - 3 + rd, gh = h0 - 3 + rh;
            const int rix = base + gd * HWc + gh * Wc;        // deref'd only when guarded
            const bool tilerow = (rd >= 3 && rd < 3 + TD && rh >= 3 && rh < 3 + TH);
            if (tilerow) {
#pragma unroll
                for (int k = 0; k < 4; ++k) {
                    const int rw = g * 4 + k;
                    if (rw >= 3 && rw < 3 + TW)
                        __builtin_nontemporal_store(tn[k], &outc[rix + (w0 - 3 + rw)]);
                }
            }
            if (c < 2) {
                const bool dhok = ((unsigned)gd < (unsigned)Dc) && ((unsigned)gh < (unsigned)Hc);
                f4 zn;
#pragma unroll
                for (int k = 0; k < 4; ++k) {
                    const int gw = w0 - 3 + g * 4 + k;
                    const bool inb = dhok && ((unsigned)gw < (unsigned)Wc);
                    zn[k] = inb ? zof(tn[k], sino[rix + gw]) : 0.f;
                }
                *(f4*)&Z[li] = zn;   // in-place: t[r] only reads Z[r] (own cell)
            }
        }
        __syncthreads();
    }
}

extern "C" void kernel_launch(void* const* d_in, const int* in_sizes, int n_in,
                              void* d_out, int out_size, void* d_ws, size_t ws_size,
                              hipStream_t stream) {
    const float* image = (const float*)d_in[0];
    const float* sino  = (const float*)d_in[1];
    const float* sigma = (const float*)d_in[2];
    const float* nt    = (const float*)d_in[3];

    float* out  = (float*)d_out;
    fused3<<<dim3(NBLK), dim3(NTHR), 0, stream>>>(
        image, sino,
        out, out + (size_t)NELEM, out + 2 * (size_t)NELEM, out + 3 * (size_t)NELEM,
        sigma, nt);
}

// Round 2
// 608.242 us; speedup vs baseline: 1.1878x; 1.1878x over previous
//
#include <hip/hip_runtime.h>

// Fused 3-cascade DTV kernel, round 2.
// Changes vs round 1:
//  - W geometry: left halo 4 (RW=39) so the output tile is f4-groups [1,9)
//    -> all output stores are full aligned float4 nontemporal (round-1 scalar
//       masked stores caused WRITE_SIZE 701 MB vs 270 MB useful).
//  - Per-cascade constexpr shrinking boxes (dual 13^2/11^2/9^2, t 12^2/10^2/8^2).
//  - template<bool INTERIOR>: guard-free path for fully-interior blocks (44%).
//  - RWP 40 -> 44: rows rotate 12 banks -> fewer ds_read_b128 conflicts.
#define LAMB 0.01f
constexpr int Bc = 2, Dc = 256, Hc = 256, Wc = 128;
constexpr int HWc = Hc * Wc;                 // 32768
constexpr int NELEM = Bc * Dc * HWc;         // 16,777,216

constexpr int TD = 8, TH = 8, TW = 32;       // output tile per block
constexpr int RDm = TD + 6, RHm = TH + 6;    // 14 x 14 region rows (halo 3 each side)
constexpr int RW = 4 + TW + 3;               // 39 cols: left halo 4 (alignment), right 3
constexpr int RWP = 44;                      // padded stride (16B aligned, +12 bank rot/row)
constexpr int NROWS = RDm * RHm;             // 196
constexpr int NTHR = 1024;
constexpr int GDt = Dc / TD, GHt = Hc / TH, GWt = Wc / TW;  // 32,32,4
constexpr int NBLK = Bc * GDt * GHt * GWt;   // 8192
constexpr int LSZ = NROWS * RWP;             // 8624 floats per array

static_assert(4 * LSZ * 4 <= 160 * 1024, "LDS over 160 KiB");
static_assert(NBLK % 8 == 0, "swizzle needs nblk % 8 == 0");

typedef float f4 __attribute__((ext_vector_type(4)));

__device__ __forceinline__ float clipf(float x, float s) {
    return fminf(fmaxf(x, -s), s);
}
__device__ __forceinline__ float zof(float t, float s) { return t + LAMB * (s - t); }
// extrapolated dual update: pn = clip(pold - dz, +-sg); return pn + nt*(pn - pold)
__device__ __forceinline__ float dual_up(float pold, float dz, float sg, float ntc) {
    float pn = clipf(pold - dz, sg);
    return pn + ntc * (pn - pold);
}

// ---- dual pass, cascade C: rows [C,13-C)^2, W f4-groups [0, C==2 ? 9 : 10) ----
template <int C, bool INT>
__device__ __forceinline__ void dual_pass(
    float* __restrict__ Z, float* __restrict__ P, float* __restrict__ Q,
    float* __restrict__ S, int d0, int h0, int w0,
    float s0, float s1, float s2, float ntc)
{
    constexpr int R0 = C, NR = 13 - 2 * C;
    constexpr int NG = (C == 2) ? 9 : 10;
    constexpr int NIT = NR * NR * NG;
    for (int it = (int)threadIdx.x; it < NIT; it += NTHR) {
        const int row = it / NG, g = it - row * NG;
        const int r2 = row / NR;
        const int rd = R0 + r2, rh = R0 + (row - r2 * NR);
        const int li = (rd * RHm + rh) * RWP + g * 4;

        const f4 zc = *(const f4*)&Z[li];
        const float z5 = Z[li + 4];                 // col+4 (pad garbage contained)
        const f4 zd = *(const f4*)&Z[li + RHm * RWP];  // rd+1
        const f4 zh = *(const f4*)&Z[li + RWP];        // rh+1

        f4 po = {0.f, 0.f, 0.f, 0.f}, qo = po, so = po;
        if (C > 0) {
            po = *(const f4*)&P[li];
            qo = *(const f4*)&Q[li];
            so = *(const f4*)&S[li];
        }
        f4 pn, qn, sn;
        if (INT) {
#pragma unroll
            for (int k = 0; k < 4; ++k) {
                const float zr = (k == 3) ? z5 : zc[k + 1];
                pn[k] = dual_up(po[k], zd[k] - zc[k], s0, ntc);
                qn[k] = dual_up(qo[k], zh[k] - zc[k], s1, ntc);
                sn[k] = dual_up(so[k], zr - zc[k], s2, ntc);
            }
        } else {
            const int gd = d0 - 3 + rd, gh = h0 - 3 + rh;
            const bool dok = (unsigned)gd < (unsigned)Dc;
            const bool hok = (unsigned)gh < (unsigned)Hc;
            const bool dlast = (gd == Dc - 1), hlast = (gh == Hc - 1);
#pragma unroll
            for (int k = 0; k < 4; ++k) {
                const int gw = w0 - 4 + g * 4 + k;
                const bool inb = dok && hok && ((unsigned)gw < (unsigned)Wc);
                const float zr = (k == 3) ? z5 : zc[k + 1];
                const float dzD = dlast ? 0.f : (zd[k] - zc[k]);
                const float dzH = hlast ? 0.f : (zh[k] - zc[k]);
                const float dzW = (gw == Wc - 1) ? 0.f : (zr - zc[k]);
                pn[k] = inb ? dual_up(po[k], dzD, s0, ntc) : 0.f;
                qn[k] = inb ? dual_up(qo[k], dzH, s1, ntc) : 0.f;
                sn[k] = inb ? dual_up(so[k], dzW, s2, ntc) : 0.f;
            }
        }
        *(f4*)&P[li] = pn;
        *(f4*)&Q[li] = qn;
        *(f4*)&S[li] = sn;
    }
}

// ---- t pass, cascade C: rows [C+1,13-C)^2; C==2 is exactly the tile ----
template <int C, bool INT>
__device__ __forceinline__ void t_pass(
    const float* __restrict__ sino, float* __restrict__ outc,
    float* __restrict__ Z, float* __restrict__ P, float* __restrict__ Q,
    float* __restrict__ S, int base, int d0, int h0, int w0, float s3)
{
    constexpr int T0 = C + 1, NR = 12 - 2 * C;
    constexpr int G0 = (C == 2) ? 1 : 0;
    constexpr int NG = (C == 2) ? 8 : 10;
    constexpr int NIT = NR * NR * NG;
    for (int it = (int)threadIdx.x; it < NIT; it += NTHR) {
        const int row = it / NG, g = G0 + (it - row * NG);
        const int r2 = row / NR;
        const int rd = T0 + r2, rh = T0 + (row - r2 * NR);
        const int li = (rd * RHm + rh) * RWP + g * 4;

        const f4 pc = *(const f4*)&P[li];
        const f4 pm = *(const f4*)&P[li - RHm * RWP];  // rd-1
        const f4 qc = *(const f4*)&Q[li];
        const f4 qm = *(const f4*)&Q[li - RWP];        // rh-1
        const f4 sc = *(const f4*)&S[li];
        const float sm1 = S[li - 1];                   // col-1 (pad garbage contained)
        const f4 zc = *(const f4*)&Z[li];

        f4 tn;
#pragma unroll
        for (int k = 0; k < 4; ++k) {
            const float smk = (k == 0) ? sm1 : sc[k - 1];
            tn[k] = (pm[k] - pc[k]) + (qm[k] - qc[k]) + (smk - sc[k])
                  + clipf(zc[k], s3);
        }

        const int gd = d0 - 3 + rd, gh = h0 - 3 + rh;
        const int rix = base + gd * HWc + gh * Wc + (w0 - 4 + g * 4);
        // tile store: always full aligned float4 (tile is always in-volume)
        const bool tile = (C == 2) ||
            (((unsigned)(rd - 3) < (unsigned)TD) &&
             ((unsigned)(rh - 3) < (unsigned)TH) &&
             ((unsigned)(g - 1) < 8u));
        if (tile)
            __builtin_nontemporal_store(tn, (f4*)&outc[rix]);

        if (C < 2) {   // t -> z in place (t[r] only reads Z[r], barrier-separated)
            f4 zn;
            if (INT) {
                const f4 sn4 = *(const f4*)&sino[rix];
#pragma unroll
                for (int k = 0; k < 4; ++k) zn[k] = zof(tn[k], sn4[k]);
            } else {
                const bool dhok = ((unsigned)gd < (unsigned)Dc) &&
                                  ((unsigned)gh < (unsigned)Hc);
#pragma unroll
                for (int k = 0; k < 4; ++k) {
                    const int gw = w0 - 4 + g * 4 + k;
                    const bool inb = dhok && ((unsigned)gw < (unsigned)Wc);
                    zn[k] = inb ? zof(tn[k], sino[rix + k]) : 0.f;
                }
            }
            *(f4*)&Z[li] = zn;
        }
    }
}

template <bool INT>
__device__ __forceinline__ void run_block(
    const float* __restrict__ image, const float* __restrict__ sino,
    float* __restrict__ out0, float* __restrict__ out1,
    float* __restrict__ out2, float* __restrict__ out3,
    const float* __restrict__ sigma, const float* __restrict__ nt,
    float* __restrict__ Z, float* __restrict__ P, float* __restrict__ Q,
    float* __restrict__ S, int base, int d0, int h0, int w0)
{
    const int tid = (int)threadIdx.x;
    const float s0 = sigma[0], s1 = sigma[1], s2 = sigma[2], s3 = sigma[3];

    // ---- phase 0: z0 over full region; interior uses aligned f4 loads ----
    for (int it = tid; it < NROWS * 10; it += NTHR) {
        const int row = it / 10, g = it - row * 10;
        const int rd = row / RHm, rh = row - (row / RHm) * RHm;
        const int gd = d0 - 3 + rd, gh = h0 - 3 + rh;
        const int li = row * RWP + g * 4;
        if (INT) {
            const int gix = base + gd * HWc + gh * Wc + (w0 - 4 + g * 4);
            const f4 a = *(const f4*)&image[gix];
            const f4 b = *(const f4*)&sino[gix];
            f4 z;
#pragma unroll
            for (int k = 0; k < 4; ++k) z[k] = zof(a[k], b[k]);
            *(f4*)&Z[li] = z;
        } else {
            const bool rowok = ((unsigned)gd < (unsigned)Dc) &&
                               ((unsigned)gh < (unsigned)Hc);
            const int rbase = base + gd * HWc + gh * Wc;  // deref'd only when guarded
            f4 z;
#pragma unroll
            for (int k = 0; k < 4; ++k) {
                const int gw = w0 - 4 + g * 4 + k;
                float v = 0.f;
                if (rowok && (unsigned)gw < (unsigned)Wc)
                    v = zof(image[rbase + gw], sino[rbase + gw]);
                z[k] = v;
            }
            *(f4*)&Z[li] = z;
        }
    }
    // out0 = image tile (aligned f4 nontemporal)
    for (int it = tid; it < TD * TH * (TW / 4); it += NTHR) {
        const int g = it & 7;
        const int r = it >> 3;
        const int td = r >> 3, th = r & 7;
        const int gix = base + (d0 + td) * HWc + (h0 + th) * Wc + w0 + g * 4;
        __builtin_nontemporal_store(*(const f4*)&image[gix], (f4*)&out0[gix]);
    }
    __syncthreads();

    const float nt0 = nt[0], nt1 = nt[1], nt2 = nt[2];

    dual_pass<0, INT>(Z, P, Q, S, d0, h0, w0, s0, s1, s2, nt0);
    __syncthreads();
    t_pass<0, INT>(sino, out1, Z, P, Q, S, base, d0, h0, w0, s3);
    __syncthreads();
    dual_pass<1, INT>(Z, P, Q, S, d0, h0, w0, s0, s1, s2, nt1);
    __syncthreads();
    t_pass<1, INT>(sino, out2, Z, P, Q, S, base, d0, h0, w0, s3);
    __syncthreads();
    dual_pass<2, INT>(Z, P, Q, S, d0, h0, w0, s0, s1, s2, nt2);
    __syncthreads();
    t_pass<2, INT>(sino, out3, Z, P, Q, S, base, d0, h0, w0, s3);
}

__global__ __launch_bounds__(NTHR) void fused3(
    const float* __restrict__ image, const float* __restrict__ sino,
    float* __restrict__ out0, float* __restrict__ out1,
    float* __restrict__ out2, float* __restrict__ out3,
    const float* __restrict__ sigma, const float* __restrict__ nt)
{
    __shared__ float Z[LSZ];
    __shared__ float P[LSZ];
    __shared__ float Q[LSZ];
    __shared__ float S[LSZ];

    // XCD-contiguous swizzle (bijective: NBLK % 8 == 0)
    int bid = (int)blockIdx.x;
    bid = (bid & 7) * (NBLK >> 3) + (bid >> 3);
    const int wT = bid & (GWt - 1);
    const int hT = (bid >> 2) & (GHt - 1);
    const int dT = (bid >> 7) & (GDt - 1);
    const int b  = bid >> 12;
    const int d0 = dT * TD, h0 = hT * TH, w0 = wT * TW;
    const int base = b * Dc * HWc;

    // interior: whole padded region in-volume and away from last-index planes
    const bool interior = (dT >= 1) && (dT <= GDt - 2) &&
                          (hT >= 1) && (hT <= GHt - 2) &&
                          (wT >= 1) && (wT <= GWt - 2);
    if (interior)
        run_block<true>(image, sino, out0, out1, out2, out3, sigma, nt,
                        Z, P, Q, S, base, d0, h0, w0);
    else
        run_block<false>(image, sino, out0, out1, out2, out3, sigma, nt,
                         Z, P, Q, S, base, d0, h0, w0);
}

extern "C" void kernel_launch(void* const* d_in, const int* in_sizes, int n_in,
                              void* d_out, int out_size, void* d_ws, size_t ws_size,
                              hipStream_t stream) {
    const float* image = (const float*)d_in[0];
    const float* sino  = (const float*)d_in[1];
    const float* sigma = (const float*)d_in[2];
    const float* nt    = (const float*)d_in[3];

    float* out = (float*)d_out;
    fused3<<<dim3(NBLK), dim3(NTHR), 0, stream>>>(
        image, sino,
        out, out + (size_t)NELEM, out + 2 * (size_t)NELEM, out + 3 * (size_t)NELEM,
        sigma, nt);
}

// Round 3
// 581.651 us; speedup vs baseline: 1.2421x; 1.0457x over previous
//
#include <hip/hip_runtime.h>

// Fused 3-cascade DTV kernel, round 3: register-resident cell state.
// Each thread statically owns <=2 f4-cells of the 14x14x10 region for the
// whole kernel. z/p/q/s/sino live in registers; LDS carries only the
// cross-thread neighbor fields (z at rd+1/rh+1/col+4, p at rd-1, q at rh-1,
// s at col-1). Box/guard/garbage-containment logic identical to round 2.
#define LAMB 0.01f
constexpr int Bc = 2, Dc = 256, Hc = 256, Wc = 128;
constexpr int HWc = Hc * Wc;                 // 32768
constexpr int NELEM = Bc * Dc * HWc;         // 16,777,216

constexpr int TD = 8, TH = 8, TW = 32;       // output tile per block
constexpr int RDm = TD + 6, RHm = TH + 6;    // 14 x 14 region rows
constexpr int RWP = 44;                      // padded W stride (floats)
constexpr int NROWS = RDm * RHm;             // 196
constexpr int NGRP = 10;                     // f4 groups per row (cols 0..39)
constexpr int NCELL = NROWS * NGRP;          // 1960
constexpr int NTHR = 1024;
constexpr int GDt = Dc / TD, GHt = Hc / TH, GWt = Wc / TW;  // 32,32,4
constexpr int NBLK = Bc * GDt * GHt * GWt;   // 8192
constexpr int LSZ = NROWS * RWP;             // 8624 floats per array

static_assert(4 * LSZ * 4 <= 160 * 1024, "LDS over 160 KiB");
static_assert(NBLK % 8 == 0, "swizzle needs nblk % 8 == 0");

typedef float f4 __attribute__((ext_vector_type(4)));

__device__ __forceinline__ float clipf(float x, float s) {
    return fminf(fmaxf(x, -s), s);
}
__device__ __forceinline__ float zof(float t, float s) { return t + LAMB * (s - t); }
// extrapolated dual update: pn = clip(pold - dz, +-sg); return pn + nt*(pn - pold)
__device__ __forceinline__ float dual_up(float po, float dz, float sg, float ntc) {
    float pn = clipf(po - dz, sg);
    return pn + ntc * (pn - po);
}

struct Cell {
    f4 z, p, q, s, sn;     // register-resident state (sn = cached sino)
    int li, rix;           // LDS index / global index of k=0
    int rd, rh, g;         // region coords
    int gd, gh, gwb;       // global coords (border path only; DCE'd for interior)
};

template <bool INT>
__device__ __forceinline__ void run_block(
    const float* __restrict__ image, const float* __restrict__ sino,
    float* __restrict__ out0, float* __restrict__ out1,
    float* __restrict__ out2, float* __restrict__ out3,
    const float* __restrict__ sigma, const float* __restrict__ nt,
    float* __restrict__ Zs, float* __restrict__ Ps, float* __restrict__ Qs,
    float* __restrict__ Ss, int base, int d0, int h0, int w0)
{
    const int tid = (int)threadIdx.x;
    const float s0 = sigma[0], s1 = sigma[1], s2 = sigma[2], s3 = sigma[3];

    auto initCell = [&](int cIdx, Cell& cl) {
        const int row = cIdx / NGRP;           // divisions happen ONCE per kernel
        cl.g   = cIdx - row * NGRP;
        cl.rd  = row / RHm;
        cl.rh  = row - cl.rd * RHm;
        cl.li  = row * RWP + cl.g * 4;
        cl.gd  = d0 - 3 + cl.rd;
        cl.gh  = h0 - 3 + cl.rh;
        cl.gwb = w0 - 4 + cl.g * 4;
        cl.rix = base + cl.gd * HWc + cl.gh * Wc + cl.gwb;  // deref'd only guarded
        cl.p = (f4){0.f, 0.f, 0.f, 0.f};
        cl.q = cl.p; cl.s = cl.p;
        f4 av;
        if (INT) {
            av    = *(const f4*)&image[cl.rix];
            cl.sn = *(const f4*)&sino[cl.rix];
#pragma unroll
            for (int k = 0; k < 4; ++k) cl.z[k] = zof(av[k], cl.sn[k]);
        } else {
            const bool rowok = ((unsigned)cl.gd < (unsigned)Dc) &&
                               ((unsigned)cl.gh < (unsigned)Hc);
#pragma unroll
            for (int k = 0; k < 4; ++k) {
                const bool inb = rowok && ((unsigned)(cl.gwb + k) < (unsigned)Wc);
                float a = 0.f, b = 0.f;
                if (inb) { a = image[cl.rix + k]; b = sino[cl.rix + k]; }
                av[k] = a; cl.sn[k] = b;
                cl.z[k] = inb ? zof(a, b) : 0.f;
            }
        }
        *(f4*)&Zs[cl.li] = cl.z;
        // out0 = image tile, folded into init (owner has `av` in regs)
        const bool tile = ((unsigned)(cl.rd - 3) < (unsigned)TD) &&
                          ((unsigned)(cl.rh - 3) < (unsigned)TH) &&
                          ((unsigned)(cl.g - 1) < 8u);
        if (tile) __builtin_nontemporal_store(av, (f4*)&out0[cl.rix]);
    };

    // dual pass: rows [C,13-C)^2, groups [0,NGd)
    auto dual = [&](Cell& cl, int C, int NGd, float ntc) {
        if (cl.rd < C || cl.rd >= 13 - C || cl.rh < C || cl.rh >= 13 - C ||
            cl.g >= NGd) return;
        const f4 zd   = *(const f4*)&Zs[cl.li + RHm * RWP];  // rd+1
        const f4 zh   = *(const f4*)&Zs[cl.li + RWP];        // rh+1
        const float z5 = Zs[cl.li + 4];                      // col+4 (garbage contained)
        if (INT) {
#pragma unroll
            for (int k = 0; k < 4; ++k) {
                const float zr = (k == 3) ? z5 : cl.z[k + 1];
                cl.p[k] = dual_up(cl.p[k], zd[k] - cl.z[k], s0, ntc);
                cl.q[k] = dual_up(cl.q[k], zh[k] - cl.z[k], s1, ntc);
                cl.s[k] = dual_up(cl.s[k], zr - cl.z[k], s2, ntc);
            }
        } else {
            const bool dok = (unsigned)cl.gd < (unsigned)Dc;
            const bool hok = (unsigned)cl.gh < (unsigned)Hc;
            const bool dlast = (cl.gd == Dc - 1), hlast = (cl.gh == Hc - 1);
#pragma unroll
            for (int k = 0; k < 4; ++k) {
                const int gw = cl.gwb + k;
                const bool inb = dok && hok && ((unsigned)gw < (unsigned)Wc);
                const float zr = (k == 3) ? z5 : cl.z[k + 1];
                const float dzD = dlast ? 0.f : (zd[k] - cl.z[k]);
                const float dzH = hlast ? 0.f : (zh[k] - cl.z[k]);
                const float dzW = (gw == Wc - 1) ? 0.f : (zr - cl.z[k]);
                cl.p[k] = inb ? dual_up(cl.p[k], dzD, s0, ntc) : 0.f;
                cl.q[k] = inb ? dual_up(cl.q[k], dzH, s1, ntc) : 0.f;
                cl.s[k] = inb ? dual_up(cl.s[k], dzW, s2, ntc) : 0.f;
            }
        }
        *(f4*)&Ps[cl.li] = cl.p;
        *(f4*)&Qs[cl.li] = cl.q;
        *(f4*)&Ss[cl.li] = cl.s;
    };

    // t pass: rows [C+1,13-C)^2, groups [G0,G1); updates z in regs+LDS if updZ
    auto tpass = [&](Cell& cl, int C, int G0, int G1, float* __restrict__ outc,
                     bool updZ) {
        if (cl.rd <= C || cl.rd >= 13 - C || cl.rh <= C || cl.rh >= 13 - C ||
            cl.g < G0 || cl.g >= G1) return;
        const f4 pm    = *(const f4*)&Ps[cl.li - RHm * RWP]; // rd-1
        const f4 qm    = *(const f4*)&Qs[cl.li - RWP];       // rh-1
        const float sm1 = Ss[cl.li - 1];                     // col-1 (garbage contained)
        f4 tn;
#pragma unroll
        for (int k = 0; k < 4; ++k) {
            const float smk = (k == 0) ? sm1 : cl.s[k - 1];
            tn[k] = (pm[k] - cl.p[k]) + (qm[k] - cl.q[k]) + (smk - cl.s[k])
                  + clipf(cl.z[k], s3);
        }
        const bool tile = ((unsigned)(cl.rd - 3) < (unsigned)TD) &&
                          ((unsigned)(cl.rh - 3) < (unsigned)TH) &&
                          ((unsigned)(cl.g - 1) < 8u);
        if (tile) __builtin_nontemporal_store(tn, (f4*)&outc[cl.rix]);
        if (updZ) {
            if (INT) {
#pragma unroll
                for (int k = 0; k < 4; ++k) cl.z[k] = zof(tn[k], cl.sn[k]);
            } else {
                const bool dhok = ((unsigned)cl.gd < (unsigned)Dc) &&
                                  ((unsigned)cl.gh < (unsigned)Hc);
#pragma unroll
                for (int k = 0; k < 4; ++k) {
                    const bool inb = dhok && ((unsigned)(cl.gwb + k) < (unsigned)Wc);
                    cl.z[k] = inb ? zof(tn[k], cl.sn[k]) : 0.f;
                }
            }
            *(f4*)&Zs[cl.li] = cl.z;   // t[r] reads only own z; barrier-separated
        }
    };

    Cell cA, cB;
    const bool two = (tid + NTHR) < NCELL;
    initCell(tid, cA);
    if (two) initCell(tid + NTHR, cB);
    __syncthreads();

    const float nt0 = nt[0], nt1 = nt[1], nt2 = nt[2];

    dual(cA, 0, 10, nt0); if (two) dual(cB, 0, 10, nt0);
    __syncthreads();
    tpass(cA, 0, 0, 10, out1, true); if (two) tpass(cB, 0, 0, 10, out1, true);
    __syncthreads();
    dual(cA, 1, 10, nt1); if (two) dual(cB, 1, 10, nt1);
    __syncthreads();
    tpass(cA, 1, 0, 10, out2, true); if (two) tpass(cB, 1, 0, 10, out2, true);
    __syncthreads();
    dual(cA, 2, 9, nt2); if (two) dual(cB, 2, 9, nt2);
    __syncthreads();
    tpass(cA, 2, 1, 9, out3, false); if (two) tpass(cB, 2, 1, 9, out3, false);
}

__global__ __launch_bounds__(NTHR) void fused3(
    const float* __restrict__ image, const float* __restrict__ sino,
    float* __restrict__ out0, float* __restrict__ out1,
    float* __restrict__ out2, float* __restrict__ out3,
    const float* __restrict__ sigma, const float* __restrict__ nt)
{
    __shared__ float Zs[LSZ];
    __shared__ float Ps[LSZ];
    __shared__ float Qs[LSZ];
    __shared__ float Ss[LSZ];

    // XCD-contiguous swizzle (bijective: NBLK % 8 == 0)
    int bid = (int)blockIdx.x;
    bid = (bid & 7) * (NBLK >> 3) + (bid >> 3);
    const int wT = bid & (GWt - 1);
    const int hT = (bid >> 2) & (GHt - 1);
    const int dT = (bid >> 7) & (GDt - 1);
    const int b  = bid >> 12;
    const int d0 = dT * TD, h0 = hT * TH, w0 = wT * TW;
    const int base = b * Dc * HWc;

    const bool interior = (dT >= 1) && (dT <= GDt - 2) &&
                          (hT >= 1) && (hT <= GHt - 2) &&
                          (wT >= 1) && (wT <= GWt - 2);
    if (interior)
        run_block<true>(image, sino, out0, out1, out2, out3, sigma, nt,
                        Zs, Ps, Qs, Ss, base, d0, h0, w0);
    else
        run_block<false>(image, sino, out0, out1, out2, out3, sigma, nt,
                         Zs, Ps, Qs, Ss, base, d0, h0, w0);
}

extern "C" void kernel_launch(void* const* d_in, const int* in_sizes, int n_in,
                              void* d_out, int out_size, void* d_ws, size_t ws_size,
                              hipStream_t stream) {
    const float* image = (const float*)d_in[0];
    const float* sino  = (const float*)d_in[1];
    const float* sigma = (const float*)d_in[2];
    const float* nt    = (const float*)d_in[3];

    float* out = (float*)d_out;
    fused3<<<dim3(NBLK), dim3(NTHR), 0, stream>>>(
        image, sino,
        out, out + (size_t)NELEM, out + 2 * (size_t)NELEM, out + 3 * (size_t)NELEM,
        sigma, nt);
}